// Round 17
// baseline (376.328 us; speedup 1.0000x reference)
//
#include <hip/hip_runtime.h>
#include <cstdint>
#include <cstddef>

// ---------------------------------------------------------------------------
// 3-layer GCN + global_add_pool.
// R12 change vs R11 (365us; fill_kernel 50us, WRITE 83MB: 2 scattered 4B
// writes/edge + random dinv gather):
//  - norm factorization: gemm epilogue scales row r by dinv[r], so
//    norm_e*h[s] == dinv[d]*g[s] with g = dinv-scaled gemm output.
//    fill now writes ONLY csr_src (4B/edge, half the scattered lines, no
//    dinv reads); agg drops the per-edge norm load; agg ends with one
//    dinv[node]*acc scale.
// Unchanged: edge-parallel agg, hi/lo-split MFMA gemm, 3-phase scan,
// sorted-batch pool.
// ---------------------------------------------------------------------------

typedef __attribute__((ext_vector_type(8))) short short8b;  // 8 bf16 = 4 VGPR
typedef __attribute__((ext_vector_type(4))) float f32x4;

static inline int cdiv_i(int a, int b) { return (a + b - 1) / b; }

__device__ inline unsigned short f2bf(float f) {  // RNE f32->bf16
    union { float f; unsigned int u; } v; v.f = f;
    unsigned int r = v.u + 0x7fffu + ((v.u >> 16) & 1u);
    return (unsigned short)(r >> 16);
}
__device__ inline float bf2f(unsigned short b) {
    union { unsigned int u; float f; } v; v.u = ((unsigned int)b) << 16;
    return v.f;
}

__global__ void zero_i32_kernel(int* __restrict__ p, int n) {
    int i = blockIdx.x * 256 + threadIdx.x;
    if (i < n) p[i] = 0;
}
__global__ void count_kernel(const int* __restrict__ dst, int* __restrict__ cnt, int E) {
    int i = blockIdx.x * 256 + threadIdx.x;
    if (i < E) atomicAdd(&cnt[dst[i]], 1);
}
__global__ void dinv_kernel(const int* __restrict__ cnt, float* __restrict__ dinv, int n) {
    int i = blockIdx.x * 256 + threadIdx.x;
    if (i < n) dinv[i] = rsqrtf((float)(cnt[i] + 1));
}

// ---- 3-phase scan: per-1024-chunk sums -> 1-wave exclusive scan -> final ----
__global__ __launch_bounds__(256) void scan_blocksum_kernel(const int* __restrict__ cnt,
                                                            int* __restrict__ psum, int n) {
    __shared__ int ws[4];
    int b = blockIdx.x, tid = threadIdx.x;
    int i0 = b * 1024 + tid * 4;
    int s = 0;
    if (i0 + 3 < n) {
        int4 v = *(const int4*)(cnt + i0);
        s = v.x + v.y + v.z + v.w;
    } else {
        for (int j = 0; j < 4; ++j) if (i0 + j < n) s += cnt[i0 + j];
    }
    #pragma unroll
    for (int d = 1; d < 64; d <<= 1) s += __shfl_xor(s, d, 64);
    int lane = tid & 63, wid = tid >> 6;
    if (lane == 0) ws[wid] = s;
    __syncthreads();
    if (tid == 0) psum[b] = ws[0] + ws[1] + ws[2] + ws[3];
}

__global__ void scan_partials_kernel(const int* __restrict__ psum, int* __restrict__ pbase,
                                     int* __restrict__ off, int n, int np) {
    int lane = threadIdx.x;
    int v = (lane < np) ? psum[lane] : 0;
    int s = v;
    #pragma unroll
    for (int d = 1; d < 64; d <<= 1) {
        int u = __shfl_up(s, d, 64);
        if (lane >= d) s += u;
    }
    if (lane < np) pbase[lane] = s - v;
    if (lane == 63) off[n] = s;
}

__global__ __launch_bounds__(256) void scan_final_kernel(const int* __restrict__ cnt,
                                                         const int* __restrict__ pbase,
                                                         int* __restrict__ off, int n) {
    __shared__ int wsum[4];
    int b = blockIdx.x, tid = threadIdx.x;
    int lane = tid & 63, wid = tid >> 6;
    int i0 = b * 1024 + tid * 4;
    int v0 = (i0 + 0 < n) ? cnt[i0 + 0] : 0;
    int v1 = (i0 + 1 < n) ? cnt[i0 + 1] : 0;
    int v2 = (i0 + 2 < n) ? cnt[i0 + 2] : 0;
    int v3 = (i0 + 3 < n) ? cnt[i0 + 3] : 0;
    int local = v0 + v1 + v2 + v3;
    int s = local;
    #pragma unroll
    for (int d = 1; d < 64; d <<= 1) {
        int u = __shfl_up(s, d, 64);
        if (lane >= d) s += u;
    }
    if (lane == 63) wsum[wid] = s;
    __syncthreads();
    int woff = 0;
    for (int w = 0; w < wid; ++w) woff += wsum[w];
    int excl = pbase[b] + woff + (s - local);
    if (i0 + 0 < n) off[i0 + 0] = excl;
    if (i0 + 1 < n) off[i0 + 1] = excl + v0;
    if (i0 + 2 < n) off[i0 + 2] = excl + v0 + v1;
    if (i0 + 3 < n) off[i0 + 3] = excl + v0 + v1 + v2;
}

__global__ void copy_i32_kernel(const int* __restrict__ a, int* __restrict__ b, int n) {
    int i = blockIdx.x * 256 + threadIdx.x;
    if (i < n) b[i] = a[i];
}

// CSR fill: single 4B scattered write per edge (norm factored out entirely).
__global__ void fill_kernel(const int* __restrict__ src, const int* __restrict__ dst,
                            int* __restrict__ cursor, int* __restrict__ csr_src, int E) {
    int i = blockIdx.x * 256 + threadIdx.x;
    if (i < E) {
        int s = src[i], d = dst[i];
        int pos = atomicAdd(&cursor[d], 1);
        csr_src[pos] = s;
    }
}

// x fp32 -> xhi/xlo bf16 (4 elems/thread)
__global__ void split_x_kernel(const float* __restrict__ x,
                               unsigned short* __restrict__ xh,
                               unsigned short* __restrict__ xl, int n4) {
    int i = blockIdx.x * 256 + threadIdx.x;
    if (i >= n4) return;
    float4 v = ((const float4*)x)[i];
    unsigned short h0 = f2bf(v.x), h1 = f2bf(v.y), h2 = f2bf(v.z), h3 = f2bf(v.w);
    unsigned short l0 = f2bf(v.x - bf2f(h0)), l1 = f2bf(v.y - bf2f(h1));
    unsigned short l2 = f2bf(v.z - bf2f(h2)), l3 = f2bf(v.w - bf2f(h3));
    ushort4 hv; hv.x = h0; hv.y = h1; hv.z = h2; hv.w = h3;
    ushort4 lv; lv.x = l0; lv.y = l1; lv.z = l2; lv.w = l3;
    ((ushort4*)xh)[i] = hv;
    ((ushort4*)xl)[i] = lv;
}

// W[128][128] fp32 (row k, col n) -> hi/lo bf16 in MFMA B-fragment order:
// idx = ((kt*8+ct)*64 + lane)*8 + j  <->  k = kt*32+(lane>>4)*8+j, n = ct*16+(lane&15)
__global__ void split_w_kernel(const float* __restrict__ W,
                               unsigned short* __restrict__ Wh,
                               unsigned short* __restrict__ Wl) {
    int t = blockIdx.x * 256 + threadIdx.x;  // 0..16383
    if (t >= 16384) return;
    int j = t & 7, lane = (t >> 3) & 63, ct = (t >> 9) & 7, kt = (t >> 12) & 3;
    int k = kt * 32 + (lane >> 4) * 8 + j;
    int nn = ct * 16 + (lane & 15);
    float w = W[k * 128 + nn];
    unsigned short h = f2bf(w);
    Wh[t] = h;
    Wl[t] = f2bf(w - bf2f(h));
}

// g[n,128] = dinv[row] * ((Ahi+Alo) @ (Whi+Wlo)), 3 bf16 MFMA products.
// Wave = 16 rows x 128 cols; block = 4 waves = 64 rows; grid = cdiv(n,64).
// Row scale by dinv implements the norm factorization (see header comment).
__global__ __launch_bounds__(256) void gemm_mfma_kernel(
    const unsigned short* __restrict__ Ahi, const unsigned short* __restrict__ Alo,
    const unsigned short* __restrict__ Whf, const unsigned short* __restrict__ Wlf,
    const float* __restrict__ dinv,
    unsigned short* __restrict__ hout, int n) {
    int wave = threadIdx.x >> 6, lane = threadIdx.x & 63;
    int r0 = blockIdx.x * 64 + wave * 16;
    int arow = r0 + (lane & 15);
    int la = min(arow, n - 1);
    int kgrp = (lane >> 4) * 8;

    f32x4 acc[8];
    #pragma unroll
    for (int c = 0; c < 8; ++c) acc[c] = (f32x4){0.f, 0.f, 0.f, 0.f};

    #pragma unroll
    for (int kt = 0; kt < 4; ++kt) {
        int koff = kt * 32 + kgrp;
        short8b a_h = *(const short8b*)(Ahi + (size_t)la * 128 + koff);
        short8b a_l = *(const short8b*)(Alo + (size_t)la * 128 + koff);
        const unsigned short* wb = Whf + ((size_t)(kt * 8) * 64 + lane) * 8;
        const unsigned short* lb = Wlf + ((size_t)(kt * 8) * 64 + lane) * 8;
        #pragma unroll
        for (int ct = 0; ct < 8; ++ct) {
            short8b wh = *(const short8b*)(wb + (size_t)ct * 512);
            short8b wl = *(const short8b*)(lb + (size_t)ct * 512);
            acc[ct] = __builtin_amdgcn_mfma_f32_16x16x32_bf16(a_h, wh, acc[ct], 0, 0, 0);
            acc[ct] = __builtin_amdgcn_mfma_f32_16x16x32_bf16(a_l, wh, acc[ct], 0, 0, 0);
            acc[ct] = __builtin_amdgcn_mfma_f32_16x16x32_bf16(a_h, wl, acc[ct], 0, 0, 0);
        }
    }
    // D layout: row = (lane>>4)*4 + reg, col = lane&15  [verified on HW in R6]
    int rb = r0 + (lane >> 4) * 4;
    int col = lane & 15;
    float dv[4];
    #pragma unroll
    for (int i = 0; i < 4; ++i) dv[i] = dinv[min(rb + i, n - 1)];
    #pragma unroll
    for (int ct = 0; ct < 8; ++ct)
        #pragma unroll
        for (int i = 0; i < 4; ++i) {
            int rr = rb + i;
            if (rr < n) hout[(size_t)rr * 128 + ct * 16 + col] = f2bf(acc[ct][i] * dv[i]);
        }
}

// Edge-parallel aggregation over dinv-scaled rows g:
//   out[d] = dinv[d] * (sum_e g[src_e] + g[d]) + bias.
// Wave = 1 node; ep=lane>>4 gives 4 edges in flight; cg=lane&15 covers bf16
// cols [cg*8, cg*8+8) via 16B gathers. Per-edge: ONE csr_src load + row gather.
// MODE 0: write bf16 hi/lo pair (next GEMM's A). MODE 1: write fp32 row.
template <int RELU, int MODE>
__global__ __launch_bounds__(256) void agg_kernel(
    const unsigned short* __restrict__ h, const int* __restrict__ off,
    const int* __restrict__ csr_src,
    const float* __restrict__ dinv, const float* __restrict__ bias,
    unsigned short* __restrict__ ah, unsigned short* __restrict__ al,
    float* __restrict__ cf32, int n) {
    int node = blockIdx.x * 4 + (threadIdx.x >> 6);
    if (node >= n) return;
    int lane = threadIdx.x & 63;
    int ep = lane >> 4;
    int cg = lane & 15;
    int c0 = cg * 8;

    float acc[8];
    #pragma unroll
    for (int j = 0; j < 8; ++j) acc[j] = 0.f;

    if (ep == 0) {  // self-loop term: + g[node]
        short8b v = *(const short8b*)(h + (size_t)node * 128 + c0);
        #pragma unroll
        for (int j = 0; j < 8; ++j) acc[j] = bf2f((unsigned short)v[j]);
    }
    int e0 = off[node], e1 = off[node + 1];
    for (int e = e0 + ep; e < e1; e += 4) {
        int s = csr_src[e];
        short8b v = *(const short8b*)(h + (size_t)s * 128 + c0);
        #pragma unroll
        for (int j = 0; j < 8; ++j) acc[j] += bf2f((unsigned short)v[j]);
    }
    // reduce across the 4 ep groups (lane bits 4,5)
    #pragma unroll
    for (int j = 0; j < 8; ++j) {
        acc[j] += __shfl_xor(acc[j], 16, 64);
        acc[j] += __shfl_xor(acc[j], 32, 64);
    }
    if (ep == 0) {
        float dn = dinv[node];
        float r[8];
        #pragma unroll
        for (int j = 0; j < 8; ++j) {
            r[j] = fmaf(dn, acc[j], bias[c0 + j]);
            if (RELU) r[j] = fmaxf(r[j], 0.f);
        }
        if (MODE == 1) {  // fp32 row for pooling pass
            float4 lo = make_float4(r[0], r[1], r[2], r[3]);
            float4 hi = make_float4(r[4], r[5], r[6], r[7]);
            *(float4*)(cf32 + (size_t)node * 128 + c0) = lo;
            *(float4*)(cf32 + (size_t)node * 128 + c0 + 4) = hi;
        } else {
            short8b hv, lv;
            #pragma unroll
            for (int j = 0; j < 8; ++j) {
                unsigned short hb = f2bf(r[j]);
                hv[j] = (short)hb;
                lv[j] = (short)f2bf(r[j] - bf2f(hb));
            }
            *(short8b*)(ah + (size_t)node * 128 + c0) = hv;
            *(short8b*)(al + (size_t)node * 128 + c0) = lv;
        }
    }
}

// global_add_pool over SORTED batch ids: one block per graph.
__global__ __launch_bounds__(256) void pool_kernel(const float* __restrict__ hsrc,
                                                   const int* __restrict__ batch,
                                                   float* __restrict__ out, int n) {
    __shared__ int s_lo, s_hi;
    __shared__ float red[4][128];
    int g = blockIdx.x;
    if (threadIdx.x == 0) {
        int lo = 0, hi = n;
        while (lo < hi) { int m = (lo + hi) >> 1; if (batch[m] < g) lo = m + 1; else hi = m; }
        s_lo = lo;
        lo = 0; hi = n;
        while (lo < hi) { int m = (lo + hi) >> 1; if (batch[m] < g + 1) lo = m + 1; else hi = m; }
        s_hi = lo;
    }
    __syncthreads();
    int lo = s_lo, hi = s_hi;
    int wave = threadIdx.x >> 6, lane = threadIdx.x & 63;
    int c2 = lane * 2;
    float ax = 0.f, ay = 0.f;
    for (int i = lo + wave; i < hi; i += 4) {
        float2 v = *(const float2*)(hsrc + (size_t)i * 128 + c2);
        ax += v.x; ay += v.y;
    }
    red[wave][c2] = ax;
    red[wave][c2 + 1] = ay;
    __syncthreads();
    if (wave == 0) {
        float a = red[0][c2] + red[1][c2] + red[2][c2] + red[3][c2];
        float b = red[0][c2 + 1] + red[1][c2 + 1] + red[2][c2 + 1] + red[3][c2 + 1];
        *(float2*)(out + (size_t)g * 128 + c2) = make_float2(a, b);
    }
}

extern "C" void kernel_launch(void* const* d_in, const int* in_sizes, int n_in,
                              void* d_out, int out_size, void* d_ws, size_t ws_size,
                              hipStream_t stream) {
    const float* x   = (const float*)d_in[0];
    const int*   ei  = (const int*)d_in[1];
    const int*   bat = (const int*)d_in[2];
    const float* W1  = (const float*)d_in[3];
    const float* b1  = (const float*)d_in[4];
    const float* W2  = (const float*)d_in[5];
    const float* b2  = (const float*)d_in[6];
    const float* W3  = (const float*)d_in[7];
    const float* b3  = (const float*)d_in[8];
    float* outp = (float*)d_out;

    const int N = in_sizes[0] / 128;   // 50000
    const int E = in_sizes[1] / 2;     // 800000
    const int NG = out_size / 128;     // 512 graphs
    const int* src = ei;
    const int* dst = ei + E;
    const int NP = cdiv_i(N, 1024);    // scan partial count (49)

    char* p = (char*)d_ws;
    auto alloc = [&](size_t bytes) -> void* {
        void* r = (void*)p;
        p += (bytes + 255) & ~(size_t)255;
        return r;
    };
    int*   cnt      = (int*)alloc((size_t)N * 4);
    int*   off      = (int*)alloc((size_t)(N + 1) * 4);
    int*   cursor   = (int*)alloc((size_t)N * 4);
    float* dinv     = (float*)alloc((size_t)N * 4);
    int*   psum     = (int*)alloc((size_t)(NP + 1) * 4);
    int*   pbase    = (int*)alloc((size_t)(NP + 1) * 4);
    int*   csr_src  = (int*)alloc((size_t)E * 4);
    unsigned short* Hb = (unsigned short*)alloc((size_t)N * 128 * 2);  // gemm out / agg in
    unsigned short* Ah = (unsigned short*)alloc((size_t)N * 128 * 2);  // agg out hi / x hi
    unsigned short* Al = (unsigned short*)alloc((size_t)N * 128 * 2);  // agg out lo / x lo
    float* Cf = (float*)alloc((size_t)N * 128 * 4);                    // layer-3 fp32 rows
    unsigned short* W1h = (unsigned short*)alloc(16384 * 2);
    unsigned short* W1l = (unsigned short*)alloc(16384 * 2);
    unsigned short* W2h = (unsigned short*)alloc(16384 * 2);
    unsigned short* W2l = (unsigned short*)alloc(16384 * 2);
    unsigned short* W3h = (unsigned short*)alloc(16384 * 2);
    unsigned short* W3l = (unsigned short*)alloc(16384 * 2);

    // ---- setup: degrees, dinv, CSR, operand splits ----
    hipLaunchKernelGGL(zero_i32_kernel, dim3(cdiv_i(N, 256)), dim3(256), 0, stream, cnt, N);
    hipLaunchKernelGGL(count_kernel, dim3(cdiv_i(E, 256)), dim3(256), 0, stream, dst, cnt, E);
    hipLaunchKernelGGL(dinv_kernel, dim3(cdiv_i(N, 256)), dim3(256), 0, stream, cnt, dinv, N);
    hipLaunchKernelGGL(scan_blocksum_kernel, dim3(NP), dim3(256), 0, stream, cnt, psum, N);
    hipLaunchKernelGGL(scan_partials_kernel, dim3(1), dim3(64), 0, stream,
                       psum, pbase, off, N, NP);
    hipLaunchKernelGGL(scan_final_kernel, dim3(NP), dim3(256), 0, stream, cnt, pbase, off, N);
    hipLaunchKernelGGL(copy_i32_kernel, dim3(cdiv_i(N, 256)), dim3(256), 0, stream, off, cursor, N);
    hipLaunchKernelGGL(fill_kernel, dim3(cdiv_i(E, 256)), dim3(256), 0, stream,
                       src, dst, cursor, csr_src, E);
    hipLaunchKernelGGL(split_x_kernel, dim3(cdiv_i(N * 32, 256)), dim3(256), 0, stream,
                       x, Ah, Al, N * 32);
    hipLaunchKernelGGL(split_w_kernel, dim3(64), dim3(256), 0, stream, W1, W1h, W1l);
    hipLaunchKernelGGL(split_w_kernel, dim3(64), dim3(256), 0, stream, W2, W2h, W2l);
    hipLaunchKernelGGL(split_w_kernel, dim3(64), dim3(256), 0, stream, W3, W3h, W3l);

    const int gemm_grid = cdiv_i(N, 64);
    const int agg_grid  = cdiv_i(N, 4);

    // ---- layer 1 ----
    hipLaunchKernelGGL(gemm_mfma_kernel, dim3(gemm_grid), dim3(256), 0, stream,
                       Ah, Al, W1h, W1l, dinv, Hb, N);
    hipLaunchKernelGGL((agg_kernel<1, 0>), dim3(agg_grid), dim3(256), 0, stream,
                       Hb, off, csr_src, dinv, b1, Ah, Al, Cf, N);
    // ---- layer 2 ----
    hipLaunchKernelGGL(gemm_mfma_kernel, dim3(gemm_grid), dim3(256), 0, stream,
                       Ah, Al, W2h, W2l, dinv, Hb, N);
    hipLaunchKernelGGL((agg_kernel<1, 0>), dim3(agg_grid), dim3(256), 0, stream,
                       Hb, off, csr_src, dinv, b2, Ah, Al, Cf, N);
    // ---- layer 3: fp32 rows, then atomic-free pooling ----
    hipLaunchKernelGGL(gemm_mfma_kernel, dim3(gemm_grid), dim3(256), 0, stream,
                       Ah, Al, W3h, W3l, dinv, Hb, N);
    hipLaunchKernelGGL((agg_kernel<0, 1>), dim3(agg_grid), dim3(256), 0, stream,
                       Hb, off, csr_src, dinv, b3, Ah, Al, Cf, N);
    hipLaunchKernelGGL(pool_kernel, dim3(NG), dim3(256), 0, stream, Cf, bat, outp, N);
}